// Round 11
// baseline (121.166 us; speedup 1.0000x reference)
//
#include <hip/hip_runtime.h>
#include <math.h>

// PRT order-3 SH projection: out[r][k] = clip(w * sum_s sh_k(th,ph)*vis, -2, 2)
//
// 4 rays per wave: lane l = (group g = l>>4 -> ray, slot t = l&15).
// Each lane loads 16 samples of its ray as 4x float4 per array (12 loads,
// 192 B/lane, all issued upfront for MLP). Multi-value butterfly over the
// 16-lane group (masks 1,2,4,8; 15 shuffles for 4 rays) leaves lane l with
// coefficient (l&15) of ray g; store is one coalesced 256 B per wave.
//
// Round-11 change vs round-10 (only change): __sincosf -> __sinf/__cosf
// (native v_sin_f32/v_cos_f32 + 1/2pi scale, no range reduction; inputs
// are phi in [0,2pi), theta in [0,pi]). Theory: kernel is VALU-issue-bound
// on the __sincosf expansion (~13 extra instr/sample), not memory-bound.

__global__ __launch_bounds__(256) void prt_kernel(
    const float* __restrict__ vis,
    const float* __restrict__ phi,
    const float* __restrict__ theta,
    const int* __restrict__ n_ptr,
    float* __restrict__ out,
    int n_rays)
{
    const int lane = threadIdx.x & 63;
    const int gwv  = (blockIdx.x * 256 + threadIdx.x) >> 6;  // global wave id
    const int ray0 = gwv * 4;
    if (ray0 >= n_rays) return;

    const int g = lane >> 4;       // ray within wave
    const int t = lane & 15;       // slot within 16-lane group
    const int sbase = (ray0 + g) * 256 + t * 4;

    // All 12 loads issued before any compute (max memory-level parallelism).
    float4 ph[4], th[4], vv[4];
    #pragma unroll
    for (int j = 0; j < 4; ++j) {
        const int a = sbase + 64 * j;
        ph[j] = *reinterpret_cast<const float4*>(phi + a);
        th[j] = *reinterpret_cast<const float4*>(theta + a);
        vv[j] = *reinterpret_cast<const float4*>(vis + a);
    }

    // acc[k], k-th SH basis sans constant:
    // 0:1  1:s*sp  2:x  3:s*cp  4:s^2*sin2  5:xs*sp  6:(1.5x^2-.5)
    // 7:xs*cp  8:s^2*cos2  9:s^3*sin3  10:xs^2*sin2  11:s(5x^2-1)*sp
    // 12:x(2.5x^2-1.5)  13:s(5x^2-1)*cp  14:xs^2*cos2  15:s^3*cos3
    float acc[16];
    #pragma unroll
    for (int i = 0; i < 16; ++i) acc[i] = 0.0f;

    #pragma unroll
    for (int j = 0; j < 4; ++j) {
        const float* phs = reinterpret_cast<const float*>(&ph[j]);
        const float* ths = reinterpret_cast<const float*>(&th[j]);
        const float* vvs = reinterpret_cast<const float*>(&vv[j]);
        #pragma unroll
        for (int e = 0; e < 4; ++e) {
            // theta in [0,pi], phi in [0,2pi): native trig, no range reduction.
            const float s  = __sinf(ths[e]);    // sin(theta) >= 0
            const float x  = __cosf(ths[e]);    // cos(theta)
            const float sp = __sinf(phs[e]);
            const float cp = __cosf(phs[e]);

            const float sq = s * s;
            const float s2 = 2.0f * sp * cp;              // sin 2phi
            const float c2 = fmaf(-2.0f * sp, sp, 1.0f);  // cos 2phi
            const float s3 = fmaf(s2, cp, c2 * sp);       // sin 3phi
            const float c3 = fmaf(-s2, sp, c2 * cp);      // cos 3phi

            const float v    = vvs[e];
            const float t1   = v * s;
            const float vx   = v * x;
            const float t2   = vx * s;
            const float vsq  = v * sq;
            const float vxsq = vx * sq;
            const float vsqs = vsq * s;

            const float x2  = x * x;
            const float P20 = fmaf(1.5f, x2, -0.5f);
            const float q1  = fmaf(5.0f, x2, -1.0f);
            const float r30 = fmaf(2.5f, x2, -1.5f);
            const float t1q = t1 * q1;

            acc[0]  += v;
            acc[1]   = fmaf(t1,   sp,  acc[1]);
            acc[2]  += vx;
            acc[3]   = fmaf(t1,   cp,  acc[3]);
            acc[4]   = fmaf(vsq,  s2,  acc[4]);
            acc[5]   = fmaf(t2,   sp,  acc[5]);
            acc[6]   = fmaf(v,    P20, acc[6]);
            acc[7]   = fmaf(t2,   cp,  acc[7]);
            acc[8]   = fmaf(vsq,  c2,  acc[8]);
            acc[9]   = fmaf(vsqs, s3,  acc[9]);
            acc[10]  = fmaf(vxsq, s2,  acc[10]);
            acc[11]  = fmaf(t1q,  sp,  acc[11]);
            acc[12]  = fmaf(vx,   r30, acc[12]);
            acc[13]  = fmaf(t1q,  cp,  acc[13]);
            acc[14]  = fmaf(vxsq, c2,  acc[14]);
            acc[15]  = fmaf(vsqs, c3,  acc[15]);
        }
    }

    // ---- multi-value butterfly within each 16-lane group ----
    const bool b0 = (lane & 1) != 0;
    const bool b1 = (lane & 2) != 0;
    const bool b2 = (lane & 4) != 0;
    const bool b3 = (lane & 8) != 0;

    // mask=1: 16 -> 8 values; acc[j] = coeff(2j + b0)
    #pragma unroll
    for (int j = 0; j < 8; ++j) {
        const float a0 = acc[2 * j], a1 = acc[2 * j + 1];
        const float keep = b0 ? a1 : a0;
        const float give = b0 ? a0 : a1;
        acc[j] = keep + __shfl_xor(give, 1, 64);
    }
    // mask=2: 8 -> 4; acc[j] = coeff(4j + 2b1 + b0)
    #pragma unroll
    for (int j = 0; j < 4; ++j) {
        const float a0 = acc[2 * j], a1 = acc[2 * j + 1];
        const float keep = b1 ? a1 : a0;
        const float give = b1 ? a0 : a1;
        acc[j] = keep + __shfl_xor(give, 2, 64);
    }
    // mask=4: 4 -> 2
    #pragma unroll
    for (int j = 0; j < 2; ++j) {
        const float a0 = acc[2 * j], a1 = acc[2 * j + 1];
        const float keep = b2 ? a1 : a0;
        const float give = b2 ? a0 : a1;
        acc[j] = keep + __shfl_xor(give, 4, 64);
    }
    // mask=8: 2 -> 1; r = coeff(lane & 15) for ray g, complete.
    float r;
    {
        const float keep = b3 ? acc[1] : acc[0];
        const float give = b3 ? acc[0] : acc[1];
        r = keep + __shfl_xor(give, 8, 64);
    }

    // ---- per-lane constant (coeff k = lane & 15), 15-select tree ----
    const float k01   = b0 ? -0.48860253f : 0.28209481f;
    const float k23   = b0 ? -0.48860253f : 0.48860253f;
    const float k45   = b0 ? -1.09254847f : 0.54627424f;
    const float k67   = b0 ? -1.09254847f : 0.63078316f;
    const float k89   = b0 ? -0.59004360f : 0.54627424f;
    const float k1011 = b0 ? -0.45704580f : 1.44530571f;
    const float k1213 = b0 ? -0.45704580f : 0.74635269f;
    const float k1415 = b0 ? -0.59004360f : 1.44530571f;
    const float ka = b1 ? k23 : k01;
    const float kb = b1 ? k67 : k45;
    const float kc = b1 ? k1011 : k89;
    const float kd = b1 ? k1415 : k1213;
    const float ke = b2 ? kb : ka;
    const float kf = b2 ? kd : kc;
    const float K  = b3 ? kf : ke;

    const int n = *n_ptr;
    const float w = 12.566370614359172f / (float)(n * n);  // 4*pi/n^2

    const float res = fminf(fmaxf(r * K * w, -2.0f), 2.0f);

    // lane l -> out[(ray0+g)*16 + t] = out[ray0*16 + l]: coalesced 256 B/wave
    out[ray0 * 16 + lane] = res;
}

extern "C" void kernel_launch(void* const* d_in, const int* in_sizes, int n_in,
                              void* d_out, int out_size, void* d_ws, size_t ws_size,
                              hipStream_t stream) {
    const float* vis   = (const float*)d_in[0];   // p_vis [R,S,1]
    const float* phi   = (const float*)d_in[1];   // [R,S]
    const float* theta = (const float*)d_in[2];   // [R,S]
    const int*   n_ptr = (const int*)d_in[3];     // scalar n (=16)

    float* out = (float*)d_out;                   // [R,16] f32

    const int n_rays = in_sizes[1] / 256;         // S = n*n = 256
    const int rays_per_block = 16;                // 4 waves x 4 rays
    const int blocks = (n_rays + rays_per_block - 1) / rays_per_block;
    prt_kernel<<<blocks, 256, 0, stream>>>(vis, phi, theta, n_ptr, out, n_rays);
}